// Round 1
// baseline (125.771 us; speedup 1.0000x reference)
//
#include <hip/hip_runtime.h>

// ACT-R activation recurrence.
// sp: [S=128][B=16384] f32 cumulative review times (days); w: [5] = (a,c,s,tau,h).
// m[i] = log( sum_{j<i} max((sp_i-sp_j)*86400*h, 1)^(-(c*exp(m_j)+a)) ), m[0]=-inf
// out[i-1] = 1/(1+exp((tau-m[i])/s)), i=1..127.
// Key identity: exp(m_j) == sum_j, so decay_j = c*sum_j + a (no extra exp).
//
// Block = 32 columns x 16 waves (1024 thr). Wave w computes the "rectangle"
// partial sum for i = i0+w over j<i0 (all decays known); wave 0 then serially
// resolves the 16x16 triangle + finalization. 2 barriers per tile.

constexpr int S    = 128;
constexpr int B    = 16384;
constexpr int COLS = 32;   // columns per block
constexpr int G    = 16;   // waves per block
constexpr int T    = 16;   // i-tile size (== G)

__launch_bounds__(G * 64, 8)
__global__ void actr_kernel(const float* __restrict__ sp,
                            const float* __restrict__ w,
                            float* __restrict__ out) {
    __shared__ float sps[S][COLS];   // sp * scale, per column
    __shared__ float nds[S][COLS];   // -(c*sum_j + a)  (negated decay)
    __shared__ float rect[T][COLS];  // per-tile rectangle partials

    const int tid  = threadIdx.x;
    const int wave = tid >> 6;
    const int lane = tid & 63;
    const int col  = lane & 31;   // column within block
    const int half = lane >> 5;   // 0/1: j-range split across wave halves
    const int gc0  = blockIdx.x * COLS;

    const float a = w[0], c = w[1], sv = w[2], tau = w[3], h = w[4];
    const float scale = 86400.0f * h;
    const float k_out = 1.44269504088896f / sv;   // log2(e)/s
    const float ln2   = 0.693147180559945f;

    // Stage prescaled sp into LDS (coalesced 128B rows).
    for (int idx = tid; idx < S * COLS; idx += G * 64) {
        const int j = idx >> 5, cc = idx & (COLS - 1);
        sps[j][cc] = sp[j * B + gc0 + cc] * scale;
    }
    if (tid < COLS) nds[0][tid] = -a;   // m[0] = -inf  =>  decay = a
    __syncthreads();

    for (int i0 = 0; i0 < S; i0 += T) {
        // ---- Phase 1: wave `wave` owns i = i0+wave; rectangle over j in [0,i0).
        const int   i   = i0 + wave;
        const float spi = sps[i][col];
        float acc = 0.0f;
        #pragma unroll 4
        for (int j = half; j < i0; j += 2) {
            const float t = fmaxf(spi - sps[j][col], 1.0f);
            acc += __builtin_amdgcn_exp2f(nds[j][col] * __builtin_amdgcn_logf(t));
        }
        acc += __shfl_xor(acc, 32);          // combine the two half-wave partials
        if (lane < 32) rect[wave][col] = acc;
        __syncthreads();

        // ---- Phase 2: wave 0 resolves the triangle sequentially in i.
        if (wave == 0) {
            for (int d = (i0 == 0) ? 1 : 0; d < T; ++d) {
                const int   ii   = i0 + d;
                const float spii = sps[ii][col];
                float tri = 0.0f;
                for (int j = i0 + half; j < ii; j += 2) {
                    const float t = fmaxf(spii - sps[j][col], 1.0f);
                    tri += __builtin_amdgcn_exp2f(nds[j][col] * __builtin_amdgcn_logf(t));
                }
                tri += __shfl_xor(tri, 32);
                const float sum = rect[d][col] + tri;
                if (lane < 32) {
                    nds[ii][col] = -(c * sum + a);
                    const float m = __builtin_amdgcn_logf(sum) * ln2;
                    const float e = __builtin_amdgcn_exp2f((tau - m) * k_out);
                    out[(ii - 1) * B + gc0 + col] = __builtin_amdgcn_rcpf(1.0f + e);
                }
                // same-wave LDS write->read (nds[ii]) is in-order on the DS pipe
            }
        }
        __syncthreads();
    }
}

extern "C" void kernel_launch(void* const* d_in, const int* in_sizes, int n_in,
                              void* d_out, int out_size, void* d_ws, size_t ws_size,
                              hipStream_t stream) {
    const float* sp = (const float*)d_in[0];
    const float* w  = (const float*)d_in[1];
    float*       o  = (float*)d_out;
    actr_kernel<<<dim3(B / COLS), dim3(G * 64), 0, stream>>>(sp, w, o);
}

// Round 2
// 113.362 us; speedup vs baseline: 1.1095x; 1.1095x over previous
//
#include <hip/hip_runtime.h>

// ACT-R activation recurrence, v2.
// m[i] = log( sum_{j<i} max((sp_i-sp_j)*86400*h, 1)^(-(c*exp(m_j)+a)) ), m[0]=-inf
// out[i-1] = 1/(1+exp((tau-m[i])/s)).  Identity: exp(m_j) == sum_j.
//
// Block: 32 columns, 16 waves, i-tiles of T=16.
//  phase1a (all waves): rect partial for i=i0+wave over j<i0 (decays known).
//  phase1b (all waves): precompute triangle logs Ltri (no decay dependence).
//  phase2  (waves 0-3): serial d=0..15; lanes j'=0..15 parallel over j;
//          2 columns packed per lane (float2); sum via 4x mov_dpp row_ror;
//          new decay kept in registers (lane j'==d); sentinel L=1e9 -> exp2->0
//          removes masking. Sigmoid deferred to phase3 (sum recovered from nd).

constexpr int S    = 128;
constexpr int B    = 16384;
constexpr int COLS = 32;
constexpr int T    = 16;

#define ROR_ADD(v, ctrl)                                                        \
  v += __int_as_float(__builtin_amdgcn_mov_dpp(__float_as_int(v), (ctrl), 0xf, 0xf, false))
#define REDUCE16(v)                                                             \
  do { ROR_ADD(v, 0x128); ROR_ADD(v, 0x124); ROR_ADD(v, 0x122); ROR_ADD(v, 0x121); } while (0)

__launch_bounds__(1024, 8)
__global__ void actr_kernel(const float* __restrict__ sp,
                            const float* __restrict__ w,
                            float* __restrict__ out) {
    __shared__ float sps[S * COLS];      // [j][col], 16KB
    __shared__ float nds[S * COLS];      // [j][col], 16KB   nd = -(c*sum+a)
    __shared__ float rect2[T * COLS];    // [d][col], 2KB
    __shared__ float ltri[16 * 128 * 2]; // [q][p][c], p=d(d-1)/2+j', slot127=sentinel

    const int tid  = threadIdx.x;
    const int wave = tid >> 6;
    const int lane = tid & 63;
    const int col  = lane & 31;
    const int half = lane >> 5;
    const int gc0  = blockIdx.x * COLS;

    const float a = w[0], c = w[1], sv = w[2], tau = w[3], h = w[4];
    const float scale = 86400.0f * h;
    const float k_out = 1.44269504088896f / sv;  // log2(e)/s
    const float rcp_c = 1.0f / c;
    const float ln2   = 0.693147180559945f;

    // stage prescaled sp (coalesced; conflict-free LDS writes)
    for (int idx = tid; idx < S * COLS; idx += 1024) {
        const int j = idx >> 5, cc = idx & 31;
        sps[idx] = sp[j * B + gc0 + cc] * scale;
    }
    if (tid < 32) ltri[(tid >> 1) * 256 + 127 * 2 + (tid & 1)] = 1.0e9f; // sentinels
    __syncthreads();

    // phase1b task mapping (fixed per thread)
    const int t_jp  = tid & 15;
    const int t_c   = (tid >> 4) & 1;
    const int t_q   = (tid >> 5) & 15;
    const int t_dh  = tid >> 9;            // 0/1 (uniform per wave)
    const int t_col = 2 * t_q + t_c;

    // phase2 mapping (waves 0-3): group g handles column pair q = wave*4+g
    const int p_g  = lane >> 4;
    const int p_jp = lane & 15;
    const int p_q  = wave * 4 + p_g;
    float ndx = -1.0f, ndy = -1.0f;        // decays held in-register per j'-slot

    for (int i0 = 0; i0 < S; i0 += T) {
        // ---- phase 1a: rectangle partials, i = i0 + wave, j in [0, i0)
        const float spi = sps[(i0 + wave) * 32 + col];
        float acc = 0.0f;
        #pragma unroll 4
        for (int j = half; j < i0; j += 2) {
            const float spj = sps[j * 32 + col];
            const float nd  = nds[j * 32 + col];
            const float t   = fmaxf(spi - spj, 1.0f);
            acc += __builtin_amdgcn_exp2f(nd * __builtin_amdgcn_logf(t));
        }
        acc += __shfl_xor(acc, 32);
        if (half == 0) rect2[wave * 32 + col] = acc;

        // ---- phase 1b: triangle logs (decay-independent)
        {
            const float spj = sps[(i0 + t_jp) * 32 + t_col];
            const int d0 = t_dh * 8;
            int bp = (d0 * (d0 - 1)) >> 1;
            #pragma unroll
            for (int dd = 0; dd < 8; ++dd) {
                const int d = d0 + dd;
                if (t_jp < d) {
                    const float t = fmaxf(sps[(i0 + d) * 32 + t_col] - spj, 1.0f);
                    ltri[t_q * 256 + (bp + t_jp) * 2 + t_c] = __builtin_amdgcn_logf(t);
                }
                bp += d;
            }
        }
        __syncthreads();

        // ---- phase 2: serial resolve (waves 0-3 only; 8 cols per wave)
        if (wave < 4) {
            int bp = 0;
            #pragma unroll
            for (int d = 0; d < T; ++d) {
                const int pidx = (p_jp < d) ? (bp + p_jp) : 127;
                const float2 L2 = *(const float2*)&ltri[p_q * 256 + pidx * 2];
                float cx = __builtin_amdgcn_exp2f(ndx * L2.x);
                float cy = __builtin_amdgcn_exp2f(ndy * L2.y);
                REDUCE16(cx);
                REDUCE16(cy);
                const float2 r2 = *(const float2*)&rect2[d * 32 + 2 * p_q];
                const float nnx = -fmaf(c, cx + r2.x, a);
                const float nny = -fmaf(c, cy + r2.y, a);
                if (p_jp == d) { ndx = nnx; ndy = nny; }
                if (p_jp == 15)
                    *(float2*)&nds[(i0 + d) * 32 + 2 * p_q] = make_float2(nnx, nny);
                bp += d;
            }
        }
        __syncthreads();
    }

    // ---- phase 3: recover sums from decays, apply sigmoid, store
    for (int idx = tid + 32; idx < S * COLS; idx += 1024) {
        const int i = idx >> 5, cc = idx & 31;
        const float sum = (-nds[idx] - a) * rcp_c;
        const float m   = __builtin_amdgcn_logf(sum) * ln2;
        const float e   = __builtin_amdgcn_exp2f((tau - m) * k_out);
        out[(i - 1) * B + gc0 + cc] = __builtin_amdgcn_rcpf(1.0f + e);
    }
}

extern "C" void kernel_launch(void* const* d_in, const int* in_sizes, int n_in,
                              void* d_out, int out_size, void* d_ws, size_t ws_size,
                              hipStream_t stream) {
    const float* sp = (const float*)d_in[0];
    const float* w  = (const float*)d_in[1];
    float*       o  = (float*)d_out;
    actr_kernel<<<dim3(B / COLS), dim3(1024), 0, stream>>>(sp, w, o);
}